// Round 6
// baseline (206.230 us; speedup 1.0000x reference)
//
#include <hip/hip_runtime.h>

// SeesawLoss on MI355X — R9.
// Inputs: d_in[0] = cls_score fp32 (8,16,512,512), d_in[1] = labels i32 (8,512,512),
//         d_in[2] = cum_samples fp32 (16). Output: d_out[0] = scalar loss fp32.
//
// History / evidence:
//  R3 (209 us): 1px/thread, separate final_k, no fences. seesaw ~45 us.
//  R4 (306 us): fused finalize (fence + same-word atomic all blocks wait on) —
//     the tail, not the 4px float4 loads, was the regression (proved in R7/R8).
//  R5/R6 (528/529): same tail @8192 blocks -> seesaw 361/367. R6's asm pin fixed
//     load clumping (VGPR 16->20) with zero delta -> loads were never the issue.
//  R7/R8 (205 us): zero atomics/fences; launch boundaries = ordering. seesaw ~38 us
//     of a 49-us controllable window (156 us = harness d_ws poison, immovable).
//  R9: seesaw's ~38 us closes on no single resource (VALU ~7, HBM ~11, MLP ample)
//     -> remaining suspect is per-pixel fixed cost: 17 load instrs/px at 4 B/lane
//     + one reduction tail per 64 px. Fix: 4 px/thread float4 loads (R4's plan),
//     now safe because the ONE 17-operand "+v" pin (proven R6/R8) forbids the
//     sinking that killed R4. Loads/px 4.25 at 16 B/lane, waves/tails /4.
//
// ws layout (uint32 words):
//   [0 .. 8191]      hist partials: block b, class c at word b*16+c   (32 KB)
//   [8192 .. 8207]   plog[16] = P * log(clip(hist_total + cum, 1, inf))
//   [8256 .. 12351]  per-block pairs: float2 {nll_sum, cnt_sum}, 2048 blocks
//                    (base byte 33024, 16B-aligned for float4 reads in final_k)

constexpr int   kC      = 16;
constexpr int   kHW     = 512 * 512;               // 2^18
constexpr float kP      = 0.8f;                    // mitigation exponent
constexpr float kLogEps = -4.605170185988091f;     // ln(0.01)
constexpr int   kPartW  = 0;                       // hist partials base word
constexpr int   kPlogW  = 8192;                    // plog base word
constexpr int   kPairW  = 8256;                    // pairs base word (16B aligned)

using f32x4 = __attribute__((ext_vector_type(4))) float;
using i32x4 = __attribute__((ext_vector_type(4))) int;

// 512 blocks (2/CU): block covers 16 KB of labels, 4 int4/thread, pinned clump.
// Tail: plain stores of the block's 16 counts to its private slot. No atomics.
__global__ __launch_bounds__(256) void hist_k(const int4* __restrict__ lab4,
                                              unsigned int* __restrict__ ws) {
    int base = blockIdx.x * 1024 + threadIdx.x;
    int4 v[4];
    #pragma unroll
    for (int j = 0; j < 4; ++j) v[j] = lab4[base + j * 256];   // contiguous 4 KB per iter
    asm volatile("" : "+v"(v[0].x), "+v"(v[0].y), "+v"(v[0].z), "+v"(v[0].w),
                      "+v"(v[1].x), "+v"(v[1].y), "+v"(v[1].z), "+v"(v[1].w),
                      "+v"(v[2].x), "+v"(v[2].y), "+v"(v[2].z), "+v"(v[2].w),
                      "+v"(v[3].x), "+v"(v[3].y), "+v"(v[3].z), "+v"(v[3].w));
    int cnt[16];
    #pragma unroll
    for (int c = 0; c < 16; ++c) cnt[c] = 0;
    #pragma unroll
    for (int j = 0; j < 4; ++j) {
        #pragma unroll
        for (int c = 0; c < 16; ++c)
            cnt[c] += (v[j].x == c) + (v[j].y == c) + (v[j].z == c) + (v[j].w == c);
    }
    #pragma unroll
    for (int c = 0; c < 16; ++c) {
        int x = cnt[c];
        #pragma unroll
        for (int off = 32; off > 0; off >>= 1) x += __shfl_down(x, off);
        cnt[c] = x;
    }
    __shared__ unsigned int sh[4 * 16];
    int wave = threadIdx.x >> 6, lane = threadIdx.x & 63;
    if (lane == 0) {
        #pragma unroll
        for (int c = 0; c < 16; ++c) sh[wave * 16 + c] = (unsigned)cnt[c];
    }
    __syncthreads();
    int t = threadIdx.x;
    if (t < 16)   // private slot, plain store
        ws[kPartW + blockIdx.x * 16 + t] = sh[t] + sh[16 + t] + sh[32 + t] + sh[48 + t];
}

// 1 block. Folds 512x16 partials -> plog[16]. Kernel boundary = ordering.
__global__ __launch_bounds__(256) void plog_k(const float* __restrict__ cum_in,
                                              unsigned int* __restrict__ ws) {
    __shared__ float sh[256];                      // [group][class], linear = t
    int t = threadIdx.x;
    int c = t & 15, g = t >> 4;                    // 16 groups x 16 classes
    unsigned s = 0;
    #pragma unroll 4
    for (int i = 0; i < 32; ++i)                   // group g sums 32 of 512 blocks
        s += ws[kPartW + (g * 32 + i) * 16 + c];
    sh[t] = (float)s;                              // exact: counts <= 2^21
    __syncthreads();
    if (t < 16) {
        float tot = 0.0f;
        #pragma unroll
        for (int gg = 0; gg < 16; ++gg) tot += sh[gg * 16 + t];
        float cc = fmaxf(tot + cum_in[t], 1.0f);   // clip(cum, 1, inf)
        ((float*)ws)[kPlogW + t] = kP * __logf(cc);
    }
}

// 4 pixels/thread, 2048 blocks x 256 threads. 16 float4 + 1 int4 loads issued
// first and pinned live in ONE asm (partial pins would license partial sinking).
// Adjusted logits overwrite v[c][p] in place -> peak ~90-100 VGPR under the
// 128 cap of (256,4). Tail: one plain float2 store per block.
__global__ __launch_bounds__(256, 4) void seesaw_k(const float* __restrict__ cls,
                                                   const int*   __restrict__ labels,
                                                   const float* __restrict__ plogp,
                                                   float* __restrict__ pairs) {
    __shared__ float s_red[8];
    int t   = threadIdx.x;
    int idx = blockIdx.x * 256 + t;                // float4 index; grid covers M/4
    int px0 = idx << 2;                            // 4-aligned, never crosses an image
    int b   = px0 >> 18;
    int hw  = px0 & (kHW - 1);
    const f32x4* pbase = (const f32x4*)(cls + (long long)b * kC * kHW + hw);

    f32x4 v[16];
    #pragma unroll
    for (int c = 0; c < 16; ++c) v[c] = pbase[c * (kHW / 4)];   // 16 KB/wave in flight
    i32x4 lab4 = ((const i32x4*)labels)[idx];
    // Liveness pin: all 17 vector loads issued as one clump, one vmcnt drain here.
    asm volatile("" : "+v"(v[0]),  "+v"(v[1]),  "+v"(v[2]),  "+v"(v[3]),
                      "+v"(v[4]),  "+v"(v[5]),  "+v"(v[6]),  "+v"(v[7]),
                      "+v"(v[8]),  "+v"(v[9]),  "+v"(v[10]), "+v"(v[11]),
                      "+v"(v[12]), "+v"(v[13]), "+v"(v[14]), "+v"(v[15]),
                      "+v"(lab4));

    float pl[16];
    #pragma unroll
    for (int c = 0; c < 16; ++c) pl[c] = plogp[c];  // uniform addr -> s_load (SGPRs)

    float lsum = 0.0f, lcnt = 0.0f;
    #pragma unroll
    for (int p = 0; p < 4; ++p) {
        int lab = lab4[p];
        float m1   = v[0][p];
        float llab = v[0][p];                       // select chains, no dynamic index
        float plab = pl[0];
        #pragma unroll
        for (int c = 1; c < 16; ++c) {
            float x = v[c][p];
            m1 = fmaxf(m1, x);
            if (c == lab) { llab = x; plab = pl[c]; }
        }
        float s = 0.0f;
        #pragma unroll
        for (int c = 0; c < 16; ++c) s += __expf(v[c][p] - m1);
        // log(score_mat[c]) = l[c] - K, K = max(llab, m1 + log s + log EPS)
        float K = fmaxf(llab, m1 + __logf(s) + kLogEps);

        float m2 = -3.0e38f;
        #pragma unroll
        for (int c = 0; c < 16; ++c) {
            // adj = l + log(mit) + log(comp); both clamp to 0 at c==lab -> adj==llab
            float x = v[c][p];
            float a = x + fminf(0.0f, pl[c] - plab)
                        + fmaxf(0.0f, 2.0f * (x - K));
            v[c][p] = a;                            // in-place: no extra registers
            m2 = fmaxf(m2, a);
        }
        float s2 = 0.0f;
        #pragma unroll
        for (int c = 0; c < 16; ++c) s2 += __expf(v[c][p] - m2);
        float nll = m2 + __logf(s2) - llab;         // -log_softmax(adj)[lab]

        if (lab != 0) { lsum += nll; lcnt += 1.0f; }  // ignore_index = 0
    }

    #pragma unroll
    for (int off = 32; off > 0; off >>= 1) {
        lsum += __shfl_down(lsum, off);
        lcnt += __shfl_down(lcnt, off);
    }
    int wave = t >> 6, lane = t & 63;
    if (lane == 0) { s_red[wave] = lsum; s_red[4 + wave] = lcnt; }
    __syncthreads();
    if (t == 0) {                                   // one plain 8B store per block
        float2 pr;
        pr.x = s_red[0] + s_red[1] + s_red[2] + s_red[3];
        pr.y = s_red[4] + s_red[5] + s_red[6] + s_red[7];
        ((float2*)pairs)[blockIdx.x] = pr;
    }
}

// 1 block, 256 threads: reduce 2048 float2 pairs (16 KB) -> loss.
__global__ __launch_bounds__(256) void final_k(const float* __restrict__ pairs,
                                               float* __restrict__ out) {
    __shared__ float s_red[8];
    int t = threadIdx.x;
    const float4* p4 = (const float4*)pairs;       // 1024 float4 = 2048 pairs
    float4 v[4];
    #pragma unroll
    for (int i = 0; i < 4; ++i) v[i] = p4[t + i * 256];
    asm volatile("" : "+v"(v[0].x), "+v"(v[1].x), "+v"(v[2].x), "+v"(v[3].x));
    float a = 0.0f, bb = 0.0f;
    #pragma unroll
    for (int i = 0; i < 4; ++i) { a += v[i].x + v[i].z; bb += v[i].y + v[i].w; }
    #pragma unroll
    for (int off = 32; off > 0; off >>= 1) {
        a  += __shfl_down(a, off);
        bb += __shfl_down(bb, off);
    }
    int wave = t >> 6, lane = t & 63;
    if (lane == 0) { s_red[wave] = a; s_red[4 + wave] = bb; }
    __syncthreads();
    if (t == 0)
        out[0] = (s_red[0] + s_red[1] + s_red[2] + s_red[3]) /
                 (s_red[4] + s_red[5] + s_red[6] + s_red[7]);
}

extern "C" void kernel_launch(void* const* d_in, const int* in_sizes, int n_in,
                              void* d_out, int out_size, void* d_ws, size_t ws_size,
                              hipStream_t stream) {
    const float* cls    = (const float*)d_in[0];
    const int*   labels = (const int*)d_in[1];
    const float* cum_in = (const float*)d_in[2];
    float* out = (float*)d_out;
    unsigned int* ws = (unsigned int*)d_ws;

    int M  = in_sizes[1];        // 2,097,152 pixels
    int n4 = M / 4;

    hist_k  <<<n4 / 1024, 256, 0, stream>>>((const int4*)labels, ws);
    plog_k  <<<1,         256, 0, stream>>>(cum_in, ws);
    seesaw_k<<<M / 1024,  256, 0, stream>>>(cls, labels,
                                            (const float*)ws + kPlogW,
                                            (float*)ws + kPairW);
    final_k <<<1,         256, 0, stream>>>((const float*)ws + kPairW, out);
}

// Round 7
// 205.713 us; speedup vs baseline: 1.0025x; 1.0025x over previous
//
#include <hip/hip_runtime.h>

// SeesawLoss on MI355X — R10.
// Inputs: d_in[0] = cls_score fp32 (8,16,512,512), d_in[1] = labels i32 (8,512,512),
//         d_in[2] = cum_samples fp32 (16). Output: d_out[0] = scalar loss fp32.
//
// History / evidence:
//  R7/R8 (205 us): zero atomics/fences; launch boundaries = ordering. seesaw ~38 us
//     of ~49 us controllable (156 us = harness d_ws poison fills, immovable).
//  R6 null: load-clump pin (MLP) changed nothing. R9 null: 4px/thread float4
//     (load instrs/px 17->4.25, tails /4) changed nothing. Two axes eliminated.
//  R10 tests the last actionable axis: VALU/trans work (~260 ops/px). Cuts ~20%:
//   - base-2 domain: l2 = l*log2e once; 32 exps become bare v_exp_f32, logs bare
//     v_log_f32 (plog_k emits P*log2 so mitigation stays consistent).
//   - min(0,pl-plab) = min(pl,plab) - plab; the -plab is channel-constant and
//     cancels in log-softmax -> 16 subs/px dropped, paid once in nll.
//   - v_max3 trees for both 16-wide max reductions (fmax exactly associative).
//   - plab via 16-entry LDS broadcast gather (per-wave duplicate write, no
//     barrier) instead of a 15-cndmask select chain.
//  If this nulls too -> memory-system service-rate floor (L3-resident reads at
//  ~3.6 TB/s effective) -> roofline.
//
// ws layout (uint32 words):
//   [0 .. 8191]      hist partials: block b, class c at word b*16+c   (32 KB)
//   [8192 .. 8207]   plog2[16] = P * log2(clip(hist_total + cum, 1, inf))
//   [8256 .. 12351]  per-block pairs: float2 {nll_sum, cnt_sum}, 2048 blocks

constexpr int   kC       = 16;
constexpr int   kHW      = 512 * 512;              // 2^18
constexpr float kP       = 0.8f;                   // mitigation exponent
constexpr float kLog2e   = 1.4426950408889634f;    // log2(e)
constexpr float kLn2     = 0.6931471805599453f;    // ln(2)
constexpr float kLog2Eps = -6.643856189774724f;    // log2(0.01)
constexpr int   kPartW   = 0;                      // hist partials base word
constexpr int   kPlogW   = 8192;                   // plog2 base word
constexpr int   kPairW   = 8256;                   // pairs base word (16B aligned)

using f32x4 = __attribute__((ext_vector_type(4))) float;
using i32x4 = __attribute__((ext_vector_type(4))) int;

__device__ __forceinline__ float exp2_f(float x) {     // bare v_exp_f32 (2^x)
    float r; asm("v_exp_f32 %0, %1" : "=v"(r) : "v"(x)); return r;
}
__device__ __forceinline__ float log2_f(float x) {     // bare v_log_f32 (log2 x)
    float r; asm("v_log_f32 %0, %1" : "=v"(r) : "v"(x)); return r;
}
#define MX3(a, b, c) fmaxf(fmaxf((a), (b)), (c))       // fuses to v_max3_f32

// 512 blocks (2/CU): block covers 16 KB of labels, 4 int4/thread, pinned clump.
__global__ __launch_bounds__(256) void hist_k(const int4* __restrict__ lab4,
                                              unsigned int* __restrict__ ws) {
    int base = blockIdx.x * 1024 + threadIdx.x;
    int4 v[4];
    #pragma unroll
    for (int j = 0; j < 4; ++j) v[j] = lab4[base + j * 256];   // contiguous 4 KB per iter
    asm volatile("" : "+v"(v[0].x), "+v"(v[0].y), "+v"(v[0].z), "+v"(v[0].w),
                      "+v"(v[1].x), "+v"(v[1].y), "+v"(v[1].z), "+v"(v[1].w),
                      "+v"(v[2].x), "+v"(v[2].y), "+v"(v[2].z), "+v"(v[2].w),
                      "+v"(v[3].x), "+v"(v[3].y), "+v"(v[3].z), "+v"(v[3].w));
    int cnt[16];
    #pragma unroll
    for (int c = 0; c < 16; ++c) cnt[c] = 0;
    #pragma unroll
    for (int j = 0; j < 4; ++j) {
        #pragma unroll
        for (int c = 0; c < 16; ++c)
            cnt[c] += (v[j].x == c) + (v[j].y == c) + (v[j].z == c) + (v[j].w == c);
    }
    #pragma unroll
    for (int c = 0; c < 16; ++c) {
        int x = cnt[c];
        #pragma unroll
        for (int off = 32; off > 0; off >>= 1) x += __shfl_down(x, off);
        cnt[c] = x;
    }
    __shared__ unsigned int sh[4 * 16];
    int wave = threadIdx.x >> 6, lane = threadIdx.x & 63;
    if (lane == 0) {
        #pragma unroll
        for (int c = 0; c < 16; ++c) sh[wave * 16 + c] = (unsigned)cnt[c];
    }
    __syncthreads();
    int t = threadIdx.x;
    if (t < 16)   // private slot, plain store
        ws[kPartW + blockIdx.x * 16 + t] = sh[t] + sh[16 + t] + sh[32 + t] + sh[48 + t];
}

// 1 block. Folds 512x16 partials -> plog2[16] (BASE-2). Launch boundary = ordering.
__global__ __launch_bounds__(256) void plog_k(const float* __restrict__ cum_in,
                                              unsigned int* __restrict__ ws) {
    __shared__ float sh[256];                      // [group][class], linear = t
    int t = threadIdx.x;
    int c = t & 15, g = t >> 4;                    // 16 groups x 16 classes
    unsigned s = 0;
    #pragma unroll 4
    for (int i = 0; i < 32; ++i)                   // group g sums 32 of 512 blocks
        s += ws[kPartW + (g * 32 + i) * 16 + c];
    sh[t] = (float)s;                              // exact: counts <= 2^21
    __syncthreads();
    if (t < 16) {
        float tot = 0.0f;
        #pragma unroll
        for (int gg = 0; gg < 16; ++gg) tot += sh[gg * 16 + t];
        float cc = fmaxf(tot + cum_in[t], 1.0f);   // clip(cum, 1, inf)
        ((float*)ws)[kPlogW + t] = kP * __log2f(cc);   // P * log2
    }
}

// 4 pixels/thread, 2048 blocks x 256 threads. 16 float4 + 1 int4 loads pinned in
// ONE asm (proven R6/R8/R9). All softmax math in base-2 domain; plab via LDS
// broadcast gather (per-wave duplicate write, no barrier needed).
__global__ __launch_bounds__(256, 4) void seesaw_k(const float* __restrict__ cls,
                                                   const int*   __restrict__ labels,
                                                   const float* __restrict__ plogp,
                                                   float* __restrict__ pairs) {
    __shared__ float s_red[8];
    __shared__ float s_plog2[16];
    int t   = threadIdx.x;
    int idx = blockIdx.x * 256 + t;                // float4 index; grid covers M/4
    int px0 = idx << 2;                            // 4-aligned, never crosses an image
    int b   = px0 >> 18;
    int hw  = px0 & (kHW - 1);
    const f32x4* pbase = (const f32x4*)(cls + (long long)b * kC * kHW + hw);

    f32x4 v[16];
    #pragma unroll
    for (int c = 0; c < 16; ++c) v[c] = pbase[c * (kHW / 4)];   // 16 KB/wave in flight
    i32x4 lab4 = ((const i32x4*)labels)[idx];
    // Liveness pin: all 17 vector loads issued as one clump, one vmcnt drain here.
    asm volatile("" : "+v"(v[0]),  "+v"(v[1]),  "+v"(v[2]),  "+v"(v[3]),
                      "+v"(v[4]),  "+v"(v[5]),  "+v"(v[6]),  "+v"(v[7]),
                      "+v"(v[8]),  "+v"(v[9]),  "+v"(v[10]), "+v"(v[11]),
                      "+v"(v[12]), "+v"(v[13]), "+v"(v[14]), "+v"(v[15]),
                      "+v"(lab4));

    // Every wave duplicate-writes the 16-entry plog2 table (same values, benign
    // race); same-wave write->read ordered by lgkmcnt, so NO barrier needed.
    int ln = t & 63;
    if (ln < 16) s_plog2[ln] = plogp[ln];

    float pl2[16];
    #pragma unroll
    for (int c = 0; c < 16; ++c) pl2[c] = plogp[c];  // uniform addr -> s_load (SGPR)

    float lsum = 0.0f, lcnt = 0.0f;
    #pragma unroll
    for (int p = 0; p < 4; ++p) {
        int lab = lab4[p];
        #pragma unroll
        for (int c = 0; c < 16; ++c) v[c][p] *= kLog2e;   // base-2 domain, in place

        // m1 via v_max3 tree (fmax exactly associative -> bit-identical)
        float a0 = MX3(v[0][p],  v[1][p],  v[2][p]);
        float a1 = MX3(v[3][p],  v[4][p],  v[5][p]);
        float a2 = MX3(v[6][p],  v[7][p],  v[8][p]);
        float a3 = MX3(v[9][p],  v[10][p], v[11][p]);
        float a4 = MX3(v[12][p], v[13][p], v[14][p]);
        float m1 = fmaxf(MX3(a0, a1, a2), MX3(a3, a4, v[15][p]));

        float llab2 = v[0][p];                      // select chain, no dynamic index
        #pragma unroll
        for (int c = 1; c < 16; ++c) if (c == lab) llab2 = v[c][p];
        float plab2 = s_plog2[lab];                 // LDS broadcast gather

        float s = 0.0f;
        #pragma unroll
        for (int c = 0; c < 16; ++c) s += exp2_f(v[c][p] - m1);
        // K2 = log2e * max(llab, m1 + ln s + ln EPS)
        float K2  = fmaxf(llab2, m1 + log2_f(s) + kLog2Eps);
        float nK2 = -2.0f * K2;

        // adjB = l2 + min(pl2[c], plab2) + max(0, 2*(l2-K2)); the channel-constant
        // (-plab2) is dropped here and paid once in nll (cancels in log-softmax).
        #pragma unroll
        for (int c = 0; c < 16; ++c) {
            float x = v[c][p];
            v[c][p] = x + fminf(pl2[c], plab2) + fmaxf(0.0f, fmaf(2.0f, x, nK2));
        }
        float b0 = MX3(v[0][p],  v[1][p],  v[2][p]);
        float b1 = MX3(v[3][p],  v[4][p],  v[5][p]);
        float b2 = MX3(v[6][p],  v[7][p],  v[8][p]);
        float b3 = MX3(v[9][p],  v[10][p], v[11][p]);
        float b4 = MX3(v[12][p], v[13][p], v[14][p]);
        float m2 = fmaxf(MX3(b0, b1, b2), MX3(b3, b4, v[15][p]));

        float s2 = 0.0f;
        #pragma unroll
        for (int c = 0; c < 16; ++c) s2 += exp2_f(v[c][p] - m2);
        // nll = ln2 * (m2 + log2 s2 - adjB[lab]),  adjB[lab] = llab2 + plab2
        float nll = (m2 + log2_f(s2) - llab2 - plab2) * kLn2;

        if (lab != 0) { lsum += nll; lcnt += 1.0f; }  // ignore_index = 0
    }

    #pragma unroll
    for (int off = 32; off > 0; off >>= 1) {
        lsum += __shfl_down(lsum, off);
        lcnt += __shfl_down(lcnt, off);
    }
    int wave = t >> 6, lane = t & 63;
    if (lane == 0) { s_red[wave] = lsum; s_red[4 + wave] = lcnt; }
    __syncthreads();
    if (t == 0) {                                   // one plain 8B store per block
        float2 pr;
        pr.x = s_red[0] + s_red[1] + s_red[2] + s_red[3];
        pr.y = s_red[4] + s_red[5] + s_red[6] + s_red[7];
        ((float2*)pairs)[blockIdx.x] = pr;
    }
}

// 1 block, 256 threads: reduce 2048 float2 pairs (16 KB) -> loss.
__global__ __launch_bounds__(256) void final_k(const float* __restrict__ pairs,
                                               float* __restrict__ out) {
    __shared__ float s_red[8];
    int t = threadIdx.x;
    const float4* p4 = (const float4*)pairs;       // 1024 float4 = 2048 pairs
    float4 v[4];
    #pragma unroll
    for (int i = 0; i < 4; ++i) v[i] = p4[t + i * 256];
    asm volatile("" : "+v"(v[0].x), "+v"(v[1].x), "+v"(v[2].x), "+v"(v[3].x));
    float a = 0.0f, bb = 0.0f;
    #pragma unroll
    for (int i = 0; i < 4; ++i) { a += v[i].x + v[i].z; bb += v[i].y + v[i].w; }
    #pragma unroll
    for (int off = 32; off > 0; off >>= 1) {
        a  += __shfl_down(a, off);
        bb += __shfl_down(bb, off);
    }
    int wave = t >> 6, lane = t & 63;
    if (lane == 0) { s_red[wave] = a; s_red[4 + wave] = bb; }
    __syncthreads();
    if (t == 0)
        out[0] = (s_red[0] + s_red[1] + s_red[2] + s_red[3]) /
                 (s_red[4] + s_red[5] + s_red[6] + s_red[7]);
}

extern "C" void kernel_launch(void* const* d_in, const int* in_sizes, int n_in,
                              void* d_out, int out_size, void* d_ws, size_t ws_size,
                              hipStream_t stream) {
    const float* cls    = (const float*)d_in[0];
    const int*   labels = (const int*)d_in[1];
    const float* cum_in = (const float*)d_in[2];
    float* out = (float*)d_out;
    unsigned int* ws = (unsigned int*)d_ws;

    int M  = in_sizes[1];        // 2,097,152 pixels
    int n4 = M / 4;

    hist_k  <<<n4 / 1024, 256, 0, stream>>>((const int4*)labels, ws);
    plog_k  <<<1,         256, 0, stream>>>(cum_in, ws);
    seesaw_k<<<M / 1024,  256, 0, stream>>>(cls, labels,
                                            (const float*)ws + kPlogW,
                                            (float*)ws + kPairW);
    final_k <<<1,         256, 0, stream>>>((const float*)ws + kPairW, out);
}